// Round 5
// baseline (416.022 us; speedup 1.0000x reference)
//
#include <hip/hip_runtime.h>
#include <stdint.h>
#include <math.h>

#define D_MODEL 1024
#define NHEAD   16
#define HDIM    64
#define FFDIM   4096
#define SEQ     2048
#define BATCH   2
#define NTOK    (BATCH*SEQ)
#define QKVN    (3*D_MODEL)

typedef __bf16 bf16;
typedef __attribute__((ext_vector_type(8))) __bf16 bf16x8;
typedef __attribute__((ext_vector_type(4))) __bf16 bf16x4;
typedef __attribute__((ext_vector_type(4))) float f32x4;

__device__ __forceinline__ void gld_lds16(const void* g, void* l) {
    __builtin_amdgcn_global_load_lds((__attribute__((address_space(1))) void*)g,
                                     (__attribute__((address_space(3))) void*)l,
                                     16, 0, 0);
}

__device__ __forceinline__ float fast_exp2(float x) {
#if __has_builtin(__builtin_amdgcn_exp2f)
    return __builtin_amdgcn_exp2f(x);
#else
    return __expf(x * 0.69314718056f);
#endif
}

// ---------------- all 4 weight transposes (fp32 W[K][N] -> bf16 Wt[N][K]) in ONE dispatch ----------------
__global__ __launch_bounds__(256)
void k_transpose_all(const float* __restrict__ w_qkv, const float* __restrict__ w_out,
                     const float* __restrict__ w_fc1, const float* __restrict__ w_fc2,
                     bf16* __restrict__ t_qkv, bf16* __restrict__ t_out,
                     bf16* __restrict__ t_fc1, bf16* __restrict__ t_fc2) {
    __shared__ float tile[32][33];
    int bid = blockIdx.x;
    const float* W; bf16* Wt; int K, N, ti;
    if (bid < 3072)       { W = w_qkv; Wt = t_qkv; K = 1024; N = 3072; ti = bid; }
    else if (bid < 4096)  { W = w_out; Wt = t_out; K = 1024; N = 1024; ti = bid - 3072; }
    else if (bid < 8192)  { W = w_fc1; Wt = t_fc1; K = 1024; N = 4096; ti = bid - 4096; }
    else                  { W = w_fc2; Wt = t_fc2; K = 4096; N = 1024; ti = bid - 8192; }
    int tn = N >> 5;
    int n0 = (ti % tn) * 32, k0 = (ti / tn) * 32;
    int tx = threadIdx.x, ty = threadIdx.y;
#pragma unroll
    for (int i = 0; i < 4; i++)
        tile[ty + i * 8][tx] = W[(size_t)(k0 + ty + i * 8) * N + n0 + tx];
    __syncthreads();
#pragma unroll
    for (int i = 0; i < 4; i++)
        Wt[(size_t)(n0 + ty + i * 8) * K + k0 + tx] = (bf16)tile[tx][ty + i * 8];
}

// ---------------- V transpose + MFMA-k-slot token permutation ----------------
__global__ __launch_bounds__(256)
void k_vtrans(const bf16* __restrict__ qkv, bf16* __restrict__ vT) {
    __shared__ bf16 t[32][33];
    int tok0 = blockIdx.x * 32, f0 = blockIdx.y * 32;
    int tx = threadIdx.x, ty = threadIdx.y;
#pragma unroll
    for (int i = 0; i < 4; i++)
        t[ty + i * 8][tx] = qkv[(size_t)(tok0 + ty + i * 8) * QKVN + 2 * D_MODEL + f0 + tx];
    __syncthreads();
    int s = tx;
    int pp = (s < 16) ? ((s >> 2) * 8 + (s & 3))
                      : (((s - 16) >> 2) * 8 + ((s - 16) & 3) + 4);
#pragma unroll
    for (int i = 0; i < 4; i++)
        vT[(size_t)(f0 + ty + i * 8) * NTOK + tok0 + pp] = t[tx][ty + i * 8];
}

// ---------------- LayerNorm (row = 1024 fp32) -> bf16 ----------------
__global__ __launch_bounds__(256)
void k_layernorm(const float* __restrict__ x, const float* __restrict__ g,
                 const float* __restrict__ b, bf16* __restrict__ out) {
    int row = blockIdx.x;
    int tid = threadIdx.x;
    float4 v = ((const float4*)(x + (size_t)row * D_MODEL))[tid];
    float s  = v.x + v.y + v.z + v.w;
    float ss = v.x * v.x + v.y * v.y + v.z * v.z + v.w * v.w;
#pragma unroll
    for (int off = 32; off > 0; off >>= 1) {
        s  += __shfl_down(s, off, 64);
        ss += __shfl_down(ss, off, 64);
    }
    __shared__ float red[2][4];
    __shared__ float mv[2];
    int wave = tid >> 6, lane = tid & 63;
    if (lane == 0) { red[0][wave] = s; red[1][wave] = ss; }
    __syncthreads();
    if (tid == 0) {
        float S  = red[0][0] + red[0][1] + red[0][2] + red[0][3];
        float SS = red[1][0] + red[1][1] + red[1][2] + red[1][3];
        float mu = S * (1.0f / D_MODEL);
        float var = SS * (1.0f / D_MODEL) - mu * mu;
        mv[0] = mu;
        mv[1] = rsqrtf(var + 1e-5f);
    }
    __syncthreads();
    float mu = mv[0], rs = mv[1];
    float4 gv = ((const float4*)g)[tid];
    float4 bv = ((const float4*)b)[tid];
    bf16x4 ov = { (bf16)((v.x - mu) * rs * gv.x + bv.x),
                  (bf16)((v.y - mu) * rs * gv.y + bv.y),
                  (bf16)((v.z - mu) * rs * gv.z + bv.z),
                  (bf16)((v.w - mu) * rs * gv.w + bv.w) };
    *(bf16x4*)(out + (size_t)row * D_MODEL + tid * 4) = ov;
}

// ---------------- elementwise: out[i] += p[i]  (fp32, float4) ----------------
__global__ __launch_bounds__(256)
void k_addin(float* __restrict__ out, const float* __restrict__ p, int n4) {
    int i = blockIdx.x * 256 + threadIdx.x;
    if (i < n4) {
        float4 o = ((const float4*)out)[i];
        float4 q = ((const float4*)p)[i];
        o.x += q.x; o.y += q.y; o.z += q.z; o.w += q.w;
        ((float4*)out)[i] = o;
    }
}

// ---------------- bf16 MFMA GEMM: C[M][N] = A[M][K] @ Bt[N][K]^T + bias (+res) (+gelu) ----
// SPLITK: blockIdx.z = k-chunk. chunk 0 -> bias(+res) -> outf/outb; chunk 1 -> raw fp32 partial to pbuf.
template <int DO_GELU, int DO_RES, int OUT_BF16, int BN, int SPLITK>
__global__ __launch_bounds__(256)
void k_gemm(const bf16* __restrict__ A, const bf16* __restrict__ Bt,
            const float* __restrict__ bias, const float* __restrict__ res,
            float* __restrict__ outf, bf16* __restrict__ outb,
            float* __restrict__ pbuf,
            int M, int N, int K) {
    constexpr int WN = BN / 32;                 // n 16-tiles per wave
    __shared__ bf16 As[128 * 32];
    __shared__ bf16 Bs[BN * 32];
    int tid  = threadIdx.x;
    int wave = tid >> 6, lane = tid & 63;
    int quad = lane >> 4, l16 = lane & 15;
    int m0 = blockIdx.y * 128, n0 = blockIdx.x * BN;
    int wm = (wave >> 1) * 64, wn = (wave & 1) * (BN / 2);
    int kc = (SPLITK > 1) ? blockIdx.z : 0;
    int kbeg = kc * (K / SPLITK), kend = kbeg + K / SPLITK;

    f32x4 acc[4][WN];
#pragma unroll
    for (int i = 0; i < 4; i++)
#pragma unroll
        for (int j = 0; j < WN; j++) acc[i][j] = (f32x4){0.f, 0.f, 0.f, 0.f};

    int lrow = lane >> 2;        // 0..15
    int lcol = (lane & 3) * 8;   // 0,8,16,24
    const bf16* gA0 = A + (size_t)(m0 + wave * 32 + lrow) * K + lcol;
    const bf16* gA1 = gA0 + (size_t)16 * K;
    bf16* lA0 = As + wave * 1024;
    bf16* lA1 = lA0 + 512;

    const bf16* gB0;
    const bf16* gB1 = nullptr;
    bf16 *lB0, *lB1 = nullptr;
    if constexpr (BN == 128) {
        gB0 = Bt + (size_t)(n0 + wave * 32 + lrow) * K + lcol;
        gB1 = gB0 + (size_t)16 * K;
        lB0 = Bs + wave * 1024;
        lB1 = lB0 + 512;
    } else {
        gB0 = Bt + (size_t)(n0 + wave * 16 + lrow) * K + lcol;
        lB0 = Bs + wave * 512;
    }

    for (int k0 = kbeg; k0 < kend; k0 += 32) {
        __syncthreads();
        gld_lds16(gA0 + k0, lA0);
        gld_lds16(gA1 + k0, lA1);
        gld_lds16(gB0 + k0, lB0);
        if constexpr (BN == 128) gld_lds16(gB1 + k0, lB1);
        __syncthreads();
        bf16x8 af[4], bfr[WN];
#pragma unroll
        for (int mi = 0; mi < 4; mi++)
            af[mi] = *(const bf16x8*)(As + (wm + mi * 16 + l16) * 32 + quad * 8);
#pragma unroll
        for (int ni = 0; ni < WN; ni++)
            bfr[ni] = *(const bf16x8*)(Bs + (wn + ni * 16 + l16) * 32 + quad * 8);
#pragma unroll
        for (int mi = 0; mi < 4; mi++)
#pragma unroll
            for (int ni = 0; ni < WN; ni++)
                acc[mi][ni] = __builtin_amdgcn_mfma_f32_16x16x32_bf16(af[mi], bfr[ni], acc[mi][ni], 0, 0, 0);
    }

#pragma unroll
    for (int mi = 0; mi < 4; mi++) {
        int row = m0 + wm + mi * 16 + quad * 4;
#pragma unroll
        for (int ni = 0; ni < WN; ni++) {
            int col = n0 + wn + ni * 16 + l16;
            float bb = bias[col];
#pragma unroll
            for (int r = 0; r < 4; r++) {
                size_t idx = (size_t)(row + r) * N + col;
                if (SPLITK > 1 && kc > 0) {
                    pbuf[idx] = acc[mi][ni][r];
                } else {
                    float v = acc[mi][ni][r] + bb;
                    if (DO_GELU) v = 0.5f * v * (1.0f + erff(v * 0.70710678118f));
                    if (DO_RES) v += res[idx];
                    if (OUT_BF16) outb[idx] = (bf16)v;
                    else          outf[idx] = v;
                }
            }
        }
    }
}

// ---------------- attention: transposed-S flash, fixed-max softmax, b128 V reads ----------------
__global__ __launch_bounds__(256)
void k_attention2(const bf16* __restrict__ qkv, const bf16* __restrict__ vT,
                  bf16* __restrict__ o) {
    __shared__ bf16 Ks[2][64][32];   // [hd-chunk][kv][32elem]
    __shared__ bf16 Vs[2][64][32];   // [kv-pair tp][hd][32 perm-tok]

    int tid = threadIdx.x, wave = tid >> 6, lane = tid & 63;
    int quad = lane >> 4, l16 = lane & 15;
    int bh = blockIdx.y;
    int b = bh >> 4, h = bh & 15;
    int q0 = blockIdx.x * 64 + wave * 16;

    const bf16* Qb  = qkv + (size_t)b * SEQ * QKVN + h * HDIM;
    const bf16* Kb  = Qb + D_MODEL;
    const bf16* vTb = vT + (size_t)h * HDIM * NTOK + b * SEQ;

    const float QSCALE = 0.125f * 1.44269504089f;
    bf16x8 qf[2];
#pragma unroll
    for (int c = 0; c < 2; c++) {
        bf16x8 qraw = *(const bf16x8*)(Qb + (size_t)(q0 + l16) * QKVN + c * 32 + quad * 8);
#pragma unroll
        for (int i = 0; i < 8; i++) qf[c][i] = (bf16)((float)qraw[i] * QSCALE);
    }

    const bf16* gK0 = Kb + (size_t)(wave * 16 + (lane >> 2)) * QKVN + 0 * 32 + (lane & 3) * 8;
    const bf16* gK1 = gK0 + 32;
    const bf16* gV0 = vTb + (size_t)(wave * 16 + (lane >> 2)) * NTOK + (lane & 3) * 8;
    const bf16* gV1 = gV0 + 32;
    bf16* lK0 = &Ks[0][wave * 16][0];
    bf16* lK1 = &Ks[1][wave * 16][0];
    bf16* lV0 = &Vs[0][wave * 16][0];
    bf16* lV1 = &Vs[1][wave * 16][0];

    f32x4 oacc[4];
#pragma unroll
    for (int i = 0; i < 4; i++) oacc[i] = (f32x4){0.f, 0.f, 0.f, 0.f};
    float lsum = 0.f;

    for (int kv0 = 0; kv0 < SEQ; kv0 += 64) {
        __syncthreads();
        size_t koff = (size_t)kv0 * QKVN;
        gld_lds16(gK0 + koff, lK0);
        gld_lds16(gK1 + koff, lK1);
        gld_lds16(gV0 + kv0, lV0);
        gld_lds16(gV1 + kv0, lV1);
        __syncthreads();

        f32x4 s[4];
#pragma unroll
        for (int t = 0; t < 4; t++) {
            bf16x8 af0 = *(const bf16x8*)(&Ks[0][t * 16 + l16][quad * 8]);
            bf16x8 af1 = *(const bf16x8*)(&Ks[1][t * 16 + l16][quad * 8]);
            f32x4 z = (f32x4){0.f, 0.f, 0.f, 0.f};
            z = __builtin_amdgcn_mfma_f32_16x16x32_bf16(af0, qf[0], z, 0, 0, 0);
            z = __builtin_amdgcn_mfma_f32_16x16x32_bf16(af1, qf[1], z, 0, 0, 0);
            s[t] = z;  // lane: kv = t*16 + quad*4 + r, q = l16
        }

        bf16x4 p[4];
#pragma unroll
        for (int t = 0; t < 4; t++)
#pragma unroll
            for (int r = 0; r < 4; r++) {
                float pf = fast_exp2(s[t][r]);
                lsum += pf;
                p[t][r] = (bf16)pf;
            }

#pragma unroll
        for (int tp = 0; tp < 2; tp++) {
            bf16x8 pa = __builtin_shufflevector(p[2 * tp], p[2 * tp + 1], 0, 1, 2, 3, 4, 5, 6, 7);
#pragma unroll
            for (int nt = 0; nt < 4; nt++) {
                bf16x8 vb = *(const bf16x8*)(&Vs[tp][nt * 16 + l16][quad * 8]);
                oacc[nt] = __builtin_amdgcn_mfma_f32_16x16x32_bf16(pa, vb, oacc[nt], 0, 0, 0);
            }
        }
    }

    lsum += __shfl_xor(lsum, 16, 64);
    lsum += __shfl_xor(lsum, 32, 64);
    float invl[4];
#pragma unroll
    for (int r = 0; r < 4; r++)
        invl[r] = 1.0f / __shfl(lsum, quad * 4 + r, 16);

#pragma unroll
    for (int nt = 0; nt < 4; nt++)
#pragma unroll
        for (int r = 0; r < 4; r++)
            o[(size_t)(b * SEQ + q0 + quad * 4 + r) * D_MODEL + h * HDIM + nt * 16 + l16] =
                (bf16)(oacc[nt][r] * invl[r]);
}

// ---------------- launcher ----------------
extern "C" void kernel_launch(void* const* d_in, const int* in_sizes, int n_in,
                              void* d_out, int out_size, void* d_ws, size_t ws_size,
                              hipStream_t stream) {
    const float* x     = (const float*)d_in[0];
    const float* ln1_g = (const float*)d_in[1];
    const float* ln1_b = (const float*)d_in[2];
    const float* w_qkv = (const float*)d_in[3];
    const float* b_qkv = (const float*)d_in[4];
    const float* w_out = (const float*)d_in[5];
    const float* b_out = (const float*)d_in[6];
    const float* ln2_g = (const float*)d_in[7];
    const float* ln2_b = (const float*)d_in[8];
    const float* w_fc1 = (const float*)d_in[9];
    const float* b_fc1 = (const float*)d_in[10];
    const float* w_fc2 = (const float*)d_in[11];
    const float* b_fc2 = (const float*)d_in[12];
    float* out = (float*)d_out;

    uintptr_t ws = (uintptr_t)d_ws;
    bf16* wt_qkv = (bf16*)(ws + 0);                  //  6291456 B
    bf16* wt_out = (bf16*)(ws + 6291456);            //  2097152 B
    bf16* wt_fc1 = (bf16*)(ws + 8388608);            //  8388608 B
    bf16* wt_fc2 = (bf16*)(ws + 16777216);           //  8388608 B
    bf16* hbuf   = (bf16*)(ws + 25165824);           //  8388608 B  (LN1 out; vT during attn; LN2 out)
    bf16* vT     = hbuf;
    bf16* qkv    = (bf16*)(ws + 33554432);           // 25165824 B
    bf16* attn_o = (bf16*)(ws + 58720256);           //  8388608 B
    bf16* hgelu  = (bf16*)(ws + 33554432);           // 33554432 B (overlays dead qkv+attn_o)
    // split-K partials (16777216 B each), overlaying dead regions:
    float* pb_op  = (float*)(ws + 33554432);         // out-proj partial: qkv region is dead post-attention
    float* pb_fc2 = (float*)(ws + 0);                // FC2 partial: wt_qkv+wt_out+wt_fc1 dead post-FC1

    k_transpose_all<<<12288, dim3(32, 8), 0, stream>>>(w_qkv, w_out, w_fc1, w_fc2,
                                                       wt_qkv, wt_out, wt_fc1, wt_fc2);

    k_layernorm<<<NTOK, 256, 0, stream>>>(x, ln1_g, ln1_b, hbuf);

    // QKV: 24x32 = 768 blocks, BN=128
    k_gemm<0, 0, 1, 128, 1><<<dim3(QKVN / 128, NTOK / 128), 256, 0, stream>>>(
        hbuf, wt_qkv, b_qkv, nullptr, nullptr, qkv, nullptr, NTOK, QKVN, D_MODEL);

    k_vtrans<<<dim3(NTOK / 32, D_MODEL / 32), dim3(32, 8), 0, stream>>>(qkv, vT);

    k_attention2<<<dim3(SEQ / 64, BATCH * NHEAD), 256, 0, stream>>>(qkv, vT, attn_o);

    // out-proj: BN=128, split-K=2 -> (8,32,2)=512 blocks, 16 iters/chunk
    k_gemm<0, 1, 0, 128, 2><<<dim3(D_MODEL / 128, NTOK / 128, 2), 256, 0, stream>>>(
        attn_o, wt_out, b_out, x, out, nullptr, pb_op, NTOK, D_MODEL, D_MODEL);
    k_addin<<<(NTOK * D_MODEL / 4 + 255) / 256, 256, 0, stream>>>(out, pb_op, NTOK * D_MODEL / 4);

    k_layernorm<<<NTOK, 256, 0, stream>>>(out, ln2_g, ln2_b, hbuf);

    // FC1: 1024 blocks, BN=128
    k_gemm<1, 0, 1, 128, 1><<<dim3(FFDIM / 128, NTOK / 128), 256, 0, stream>>>(
        hbuf, wt_fc1, b_fc1, nullptr, nullptr, hgelu, nullptr, NTOK, FFDIM, D_MODEL);

    // FC2: BN=128, split-K=2 -> (8,32,2)=512 blocks, 64 iters/chunk
    k_gemm<0, 1, 0, 128, 2><<<dim3(D_MODEL / 128, NTOK / 128, 2), 256, 0, stream>>>(
        hgelu, wt_fc2, b_fc2, out, out, nullptr, pb_fc2, NTOK, D_MODEL, FFDIM);
    k_addin<<<(NTOK * D_MODEL / 4 + 255) / 256, 256, 0, stream>>>(out, pb_fc2, NTOK * D_MODEL / 4);
}

// Round 6
// 364.610 us; speedup vs baseline: 1.1410x; 1.1410x over previous
//
#include <hip/hip_runtime.h>
#include <stdint.h>
#include <math.h>

#define D_MODEL 1024
#define NHEAD   16
#define HDIM    64
#define FFDIM   4096
#define SEQ     2048
#define BATCH   2
#define NTOK    (BATCH*SEQ)
#define QKVN    (3*D_MODEL)

typedef __bf16 bf16;
typedef __attribute__((ext_vector_type(8))) __bf16 bf16x8;
typedef __attribute__((ext_vector_type(4))) __bf16 bf16x4;
typedef __attribute__((ext_vector_type(4))) float f32x4;

__device__ __forceinline__ void gld_lds16(const void* g, void* l) {
    __builtin_amdgcn_global_load_lds((__attribute__((address_space(1))) void*)g,
                                     (__attribute__((address_space(3))) void*)l,
                                     16, 0, 0);
}

__device__ __forceinline__ float fast_exp2(float x) {
#if __has_builtin(__builtin_amdgcn_exp2f)
    return __builtin_amdgcn_exp2f(x);
#else
    return __expf(x * 0.69314718056f);
#endif
}

// ---------------- all 4 weight transposes (fp32 W[K][N] -> bf16 Wt[N][K]) in ONE dispatch ----------------
__global__ __launch_bounds__(256)
void k_transpose_all(const float* __restrict__ w_qkv, const float* __restrict__ w_out,
                     const float* __restrict__ w_fc1, const float* __restrict__ w_fc2,
                     bf16* __restrict__ t_qkv, bf16* __restrict__ t_out,
                     bf16* __restrict__ t_fc1, bf16* __restrict__ t_fc2) {
    __shared__ float tile[32][33];
    int bid = blockIdx.x;
    const float* W; bf16* Wt; int K, N, ti;
    if (bid < 3072)       { W = w_qkv; Wt = t_qkv; K = 1024; N = 3072; ti = bid; }
    else if (bid < 4096)  { W = w_out; Wt = t_out; K = 1024; N = 1024; ti = bid - 3072; }
    else if (bid < 8192)  { W = w_fc1; Wt = t_fc1; K = 1024; N = 4096; ti = bid - 4096; }
    else                  { W = w_fc2; Wt = t_fc2; K = 4096; N = 1024; ti = bid - 8192; }
    int tn = N >> 5;
    int n0 = (ti % tn) * 32, k0 = (ti / tn) * 32;
    int tx = threadIdx.x, ty = threadIdx.y;
#pragma unroll
    for (int i = 0; i < 4; i++)
        tile[ty + i * 8][tx] = W[(size_t)(k0 + ty + i * 8) * N + n0 + tx];
    __syncthreads();
#pragma unroll
    for (int i = 0; i < 4; i++)
        Wt[(size_t)(n0 + ty + i * 8) * K + k0 + tx] = (bf16)tile[tx][ty + i * 8];
}

// ---------------- V transpose + MFMA-k-slot token permutation ----------------
__global__ __launch_bounds__(256)
void k_vtrans(const bf16* __restrict__ qkv, bf16* __restrict__ vT) {
    __shared__ bf16 t[32][33];
    int tok0 = blockIdx.x * 32, f0 = blockIdx.y * 32;
    int tx = threadIdx.x, ty = threadIdx.y;
#pragma unroll
    for (int i = 0; i < 4; i++)
        t[ty + i * 8][tx] = qkv[(size_t)(tok0 + ty + i * 8) * QKVN + 2 * D_MODEL + f0 + tx];
    __syncthreads();
    int s = tx;
    int pp = (s < 16) ? ((s >> 2) * 8 + (s & 3))
                      : (((s - 16) >> 2) * 8 + ((s - 16) & 3) + 4);
#pragma unroll
    for (int i = 0; i < 4; i++)
        vT[(size_t)(f0 + ty + i * 8) * NTOK + tok0 + pp] = t[tx][ty + i * 8];
}

// ---------------- LayerNorm (row = 1024 fp32) -> bf16 ----------------
__global__ __launch_bounds__(256)
void k_layernorm(const float* __restrict__ x, const float* __restrict__ g,
                 const float* __restrict__ b, bf16* __restrict__ out) {
    int row = blockIdx.x;
    int tid = threadIdx.x;
    float4 v = ((const float4*)(x + (size_t)row * D_MODEL))[tid];
    float s  = v.x + v.y + v.z + v.w;
    float ss = v.x * v.x + v.y * v.y + v.z * v.z + v.w * v.w;
#pragma unroll
    for (int off = 32; off > 0; off >>= 1) {
        s  += __shfl_down(s, off, 64);
        ss += __shfl_down(ss, off, 64);
    }
    __shared__ float red[2][4];
    __shared__ float mv[2];
    int wave = tid >> 6, lane = tid & 63;
    if (lane == 0) { red[0][wave] = s; red[1][wave] = ss; }
    __syncthreads();
    if (tid == 0) {
        float S  = red[0][0] + red[0][1] + red[0][2] + red[0][3];
        float SS = red[1][0] + red[1][1] + red[1][2] + red[1][3];
        float mu = S * (1.0f / D_MODEL);
        float var = SS * (1.0f / D_MODEL) - mu * mu;
        mv[0] = mu;
        mv[1] = rsqrtf(var + 1e-5f);
    }
    __syncthreads();
    float mu = mv[0], rs = mv[1];
    float4 gv = ((const float4*)g)[tid];
    float4 bv = ((const float4*)b)[tid];
    bf16x4 ov = { (bf16)((v.x - mu) * rs * gv.x + bv.x),
                  (bf16)((v.y - mu) * rs * gv.y + bv.y),
                  (bf16)((v.z - mu) * rs * gv.z + bv.z),
                  (bf16)((v.w - mu) * rs * gv.w + bv.w) };
    *(bf16x4*)(out + (size_t)row * D_MODEL + tid * 4) = ov;
}

// ---------------- bf16 MFMA GEMM, register-staged double-buffered pipeline ----------------
// C[M][N] = A[M][K] @ Bt[N][K]^T + bias (+res) (+gelu)
// Per iter: issue next tile's global loads -> VGPRs; MFMA on current LDS buffer while loads
// fly; ds_write regs -> other buffer; ONE barrier. Overlaps load latency with compute even
// at 1 block/CU (where the global_load_lds+2-barrier structure serializes).
template <int DO_GELU, int DO_RES, int OUT_BF16, int BN>
__global__ __launch_bounds__(256)
void k_gemm(const bf16* __restrict__ A, const bf16* __restrict__ Bt,
            const float* __restrict__ bias, const float* __restrict__ res,
            float* __restrict__ outf, bf16* __restrict__ outb,
            int M, int N, int K) {
    constexpr int WN = BN / 32;                 // n 16-tiles per wave
    __shared__ bf16 As[2][128 * 32];
    __shared__ bf16 Bs[2][BN * 32];
    int tid  = threadIdx.x;
    int wave = tid >> 6, lane = tid & 63;
    int quad = lane >> 4, l16 = lane & 15;
    int m0 = blockIdx.y * 128, n0 = blockIdx.x * BN;
    int wm = (wave >> 1) * 64, wn = (wave & 1) * (BN / 2);

    f32x4 acc[4][WN];
#pragma unroll
    for (int i = 0; i < 4; i++)
#pragma unroll
        for (int j = 0; j < WN; j++) acc[i][j] = (f32x4){0.f, 0.f, 0.f, 0.f};

    int lrow = lane >> 2;        // 0..15
    int lcol = (lane & 3) * 8;   // 0,8,16,24
    const bf16* gA0 = A + (size_t)(m0 + wave * 32 + lrow) * K + lcol;
    const bf16* gA1 = gA0 + (size_t)16 * K;
    const bf16* gB0;
    const bf16* gB1 = nullptr;
    if constexpr (BN == 128) {
        gB0 = Bt + (size_t)(n0 + wave * 32 + lrow) * K + lcol;
        gB1 = gB0 + (size_t)16 * K;
    } else {
        gB0 = Bt + (size_t)(n0 + wave * 16 + lrow) * K + lcol;
    }

    // LDS elem offsets: chunk layout = 16 rows x 32 cols contiguous; lane l -> elem l*8
    int wA0 = wave * 1024 + lane * 8;
    int wA1 = wA0 + 512;
    int wB0 = (BN == 128) ? (wave * 1024 + lane * 8) : (wave * 512 + lane * 8);
    int wB1 = wB0 + 512;   // used only when BN==128

    // prologue: stage tile 0 into buffer 0
    {
        bf16x8 rA0 = *(const bf16x8*)(gA0);
        bf16x8 rA1 = *(const bf16x8*)(gA1);
        bf16x8 rB0 = *(const bf16x8*)(gB0);
        bf16x8 rB1;
        if constexpr (BN == 128) rB1 = *(const bf16x8*)(gB1);
        *(bf16x8*)(&As[0][wA0]) = rA0;
        *(bf16x8*)(&As[0][wA1]) = rA1;
        *(bf16x8*)(&Bs[0][wB0]) = rB0;
        if constexpr (BN == 128) *(bf16x8*)(&Bs[0][wB1]) = rB1;
    }
    __syncthreads();

    const bf16* curA = &As[0][0];
    const bf16* curB = &Bs[0][0];
    bf16* nxtA = &As[1][0];
    bf16* nxtB = &Bs[1][0];

    int niter = K / 32;
    for (int t = 1; t < niter; t++) {
        int k0 = t * 32;
        // issue next tile's loads (in flight during MFMA below)
        bf16x8 rA0 = *(const bf16x8*)(gA0 + k0);
        bf16x8 rA1 = *(const bf16x8*)(gA1 + k0);
        bf16x8 rB0 = *(const bf16x8*)(gB0 + k0);
        bf16x8 rB1;
        if constexpr (BN == 128) rB1 = *(const bf16x8*)(gB1 + k0);

        // compute on current buffer
        bf16x8 af[4], bfr[WN];
#pragma unroll
        for (int mi = 0; mi < 4; mi++)
            af[mi] = *(const bf16x8*)(curA + (wm + mi * 16 + l16) * 32 + quad * 8);
#pragma unroll
        for (int ni = 0; ni < WN; ni++)
            bfr[ni] = *(const bf16x8*)(curB + (wn + ni * 16 + l16) * 32 + quad * 8);
#pragma unroll
        for (int mi = 0; mi < 4; mi++)
#pragma unroll
            for (int ni = 0; ni < WN; ni++)
                acc[mi][ni] = __builtin_amdgcn_mfma_f32_16x16x32_bf16(af[mi], bfr[ni], acc[mi][ni], 0, 0, 0);

        // commit next tile to the alternate buffer (vmcnt wait lands here, after MFMAs)
        *(bf16x8*)(nxtA + wA0) = rA0;
        *(bf16x8*)(nxtA + wA1) = rA1;
        *(bf16x8*)(nxtB + wB0) = rB0;
        if constexpr (BN == 128) *(bf16x8*)(nxtB + wB1) = rB1;
        __syncthreads();

        // swap buffers
        const bf16* tA = curA; curA = nxtA; nxtA = (bf16*)tA;
        const bf16* tB = curB; curB = nxtB; nxtB = (bf16*)tB;
    }

    // final tile compute
    {
        bf16x8 af[4], bfr[WN];
#pragma unroll
        for (int mi = 0; mi < 4; mi++)
            af[mi] = *(const bf16x8*)(curA + (wm + mi * 16 + l16) * 32 + quad * 8);
#pragma unroll
        for (int ni = 0; ni < WN; ni++)
            bfr[ni] = *(const bf16x8*)(curB + (wn + ni * 16 + l16) * 32 + quad * 8);
#pragma unroll
        for (int mi = 0; mi < 4; mi++)
#pragma unroll
            for (int ni = 0; ni < WN; ni++)
                acc[mi][ni] = __builtin_amdgcn_mfma_f32_16x16x32_bf16(af[mi], bfr[ni], acc[mi][ni], 0, 0, 0);
    }

#pragma unroll
    for (int mi = 0; mi < 4; mi++) {
        int row = m0 + wm + mi * 16 + quad * 4;
#pragma unroll
        for (int ni = 0; ni < WN; ni++) {
            int col = n0 + wn + ni * 16 + l16;
            float bb = bias[col];
#pragma unroll
            for (int r = 0; r < 4; r++) {
                float v = acc[mi][ni][r] + bb;
                if (DO_GELU) v = 0.5f * v * (1.0f + erff(v * 0.70710678118f));
                size_t idx = (size_t)(row + r) * N + col;
                if (DO_RES) v += res[idx];
                if (OUT_BF16) outb[idx] = (bf16)v;
                else          outf[idx] = v;
            }
        }
    }
}

// ---------------- attention: transposed-S flash, fixed-max softmax, b128 V reads ----------------
__global__ __launch_bounds__(256)
void k_attention2(const bf16* __restrict__ qkv, const bf16* __restrict__ vT,
                  bf16* __restrict__ o) {
    __shared__ bf16 Ks[2][64][32];   // [hd-chunk][kv][32elem]
    __shared__ bf16 Vs[2][64][32];   // [kv-pair tp][hd][32 perm-tok]

    int tid = threadIdx.x, wave = tid >> 6, lane = tid & 63;
    int quad = lane >> 4, l16 = lane & 15;
    int bh = blockIdx.y;
    int b = bh >> 4, h = bh & 15;
    int q0 = blockIdx.x * 64 + wave * 16;

    const bf16* Qb  = qkv + (size_t)b * SEQ * QKVN + h * HDIM;
    const bf16* Kb  = Qb + D_MODEL;
    const bf16* vTb = vT + (size_t)h * HDIM * NTOK + b * SEQ;

    const float QSCALE = 0.125f * 1.44269504089f;
    bf16x8 qf[2];
#pragma unroll
    for (int c = 0; c < 2; c++) {
        bf16x8 qraw = *(const bf16x8*)(Qb + (size_t)(q0 + l16) * QKVN + c * 32 + quad * 8);
#pragma unroll
        for (int i = 0; i < 8; i++) qf[c][i] = (bf16)((float)qraw[i] * QSCALE);
    }

    const bf16* gK0 = Kb + (size_t)(wave * 16 + (lane >> 2)) * QKVN + 0 * 32 + (lane & 3) * 8;
    const bf16* gK1 = gK0 + 32;
    const bf16* gV0 = vTb + (size_t)(wave * 16 + (lane >> 2)) * NTOK + (lane & 3) * 8;
    const bf16* gV1 = gV0 + 32;
    bf16* lK0 = &Ks[0][wave * 16][0];
    bf16* lK1 = &Ks[1][wave * 16][0];
    bf16* lV0 = &Vs[0][wave * 16][0];
    bf16* lV1 = &Vs[1][wave * 16][0];

    f32x4 oacc[4];
#pragma unroll
    for (int i = 0; i < 4; i++) oacc[i] = (f32x4){0.f, 0.f, 0.f, 0.f};
    float lsum = 0.f;

    for (int kv0 = 0; kv0 < SEQ; kv0 += 64) {
        __syncthreads();
        size_t koff = (size_t)kv0 * QKVN;
        gld_lds16(gK0 + koff, lK0);
        gld_lds16(gK1 + koff, lK1);
        gld_lds16(gV0 + kv0, lV0);
        gld_lds16(gV1 + kv0, lV1);
        __syncthreads();

        f32x4 s[4];
#pragma unroll
        for (int t = 0; t < 4; t++) {
            bf16x8 af0 = *(const bf16x8*)(&Ks[0][t * 16 + l16][quad * 8]);
            bf16x8 af1 = *(const bf16x8*)(&Ks[1][t * 16 + l16][quad * 8]);
            f32x4 z = (f32x4){0.f, 0.f, 0.f, 0.f};
            z = __builtin_amdgcn_mfma_f32_16x16x32_bf16(af0, qf[0], z, 0, 0, 0);
            z = __builtin_amdgcn_mfma_f32_16x16x32_bf16(af1, qf[1], z, 0, 0, 0);
            s[t] = z;  // lane: kv = t*16 + quad*4 + r, q = l16
        }

        bf16x4 p[4];
#pragma unroll
        for (int t = 0; t < 4; t++)
#pragma unroll
            for (int r = 0; r < 4; r++) {
                float pf = fast_exp2(s[t][r]);
                lsum += pf;
                p[t][r] = (bf16)pf;
            }

#pragma unroll
        for (int tp = 0; tp < 2; tp++) {
            bf16x8 pa = __builtin_shufflevector(p[2 * tp], p[2 * tp + 1], 0, 1, 2, 3, 4, 5, 6, 7);
#pragma unroll
            for (int nt = 0; nt < 4; nt++) {
                bf16x8 vb = *(const bf16x8*)(&Vs[tp][nt * 16 + l16][quad * 8]);
                oacc[nt] = __builtin_amdgcn_mfma_f32_16x16x32_bf16(pa, vb, oacc[nt], 0, 0, 0);
            }
        }
    }

    lsum += __shfl_xor(lsum, 16, 64);
    lsum += __shfl_xor(lsum, 32, 64);
    float invl[4];
#pragma unroll
    for (int r = 0; r < 4; r++)
        invl[r] = 1.0f / __shfl(lsum, quad * 4 + r, 16);

#pragma unroll
    for (int nt = 0; nt < 4; nt++)
#pragma unroll
        for (int r = 0; r < 4; r++)
            o[(size_t)(b * SEQ + q0 + quad * 4 + r) * D_MODEL + h * HDIM + nt * 16 + l16] =
                (bf16)(oacc[nt][r] * invl[r]);
}

// ---------------- launcher ----------------
extern "C" void kernel_launch(void* const* d_in, const int* in_sizes, int n_in,
                              void* d_out, int out_size, void* d_ws, size_t ws_size,
                              hipStream_t stream) {
    const float* x     = (const float*)d_in[0];
    const float* ln1_g = (const float*)d_in[1];
    const float* ln1_b = (const float*)d_in[2];
    const float* w_qkv = (const float*)d_in[3];
    const float* b_qkv = (const float*)d_in[4];
    const float* w_out = (const float*)d_in[5];
    const float* b_out = (const float*)d_in[6];
    const float* ln2_g = (const float*)d_in[7];
    const float* ln2_b = (const float*)d_in[8];
    const float* w_fc1 = (const float*)d_in[9];
    const float* b_fc1 = (const float*)d_in[10];
    const float* w_fc2 = (const float*)d_in[11];
    const float* b_fc2 = (const float*)d_in[12];
    float* out = (float*)d_out;

    uintptr_t ws = (uintptr_t)d_ws;
    bf16* wt_qkv = (bf16*)(ws + 0);                  //  6291456 B
    bf16* wt_out = (bf16*)(ws + 6291456);            //  2097152 B
    bf16* wt_fc1 = (bf16*)(ws + 8388608);            //  8388608 B
    bf16* wt_fc2 = (bf16*)(ws + 16777216);           //  8388608 B
    bf16* hbuf   = (bf16*)(ws + 25165824);           //  8388608 B  (LN1 out; vT during attn; LN2 out)
    bf16* vT     = hbuf;
    bf16* qkv    = (bf16*)(ws + 33554432);           // 25165824 B
    bf16* attn_o = (bf16*)(ws + 58720256);           //  8388608 B
    bf16* hgelu  = (bf16*)(ws + 33554432);           // 33554432 B (overlays dead qkv+attn_o)

    k_transpose_all<<<12288, dim3(32, 8), 0, stream>>>(w_qkv, w_out, w_fc1, w_fc2,
                                                       wt_qkv, wt_out, wt_fc1, wt_fc2);

    k_layernorm<<<NTOK, 256, 0, stream>>>(x, ln1_g, ln1_b, hbuf);

    // QKV: 24x32 = 768 blocks, BN=128
    k_gemm<0, 0, 1, 128><<<dim3(QKVN / 128, NTOK / 128), 256, 0, stream>>>(
        hbuf, wt_qkv, b_qkv, nullptr, nullptr, qkv, NTOK, QKVN, D_MODEL);

    k_vtrans<<<dim3(NTOK / 32, D_MODEL / 32), dim3(32, 8), 0, stream>>>(qkv, vT);

    k_attention2<<<dim3(SEQ / 64, BATCH * NHEAD), 256, 0, stream>>>(qkv, vT, attn_o);

    // out-proj: BN=64 -> 512 blocks (2 blocks/CU + pipeline)
    k_gemm<0, 1, 0, 64><<<dim3(D_MODEL / 64, NTOK / 128), 256, 0, stream>>>(
        attn_o, wt_out, b_out, x, out, nullptr, NTOK, D_MODEL, D_MODEL);

    k_layernorm<<<NTOK, 256, 0, stream>>>(out, ln2_g, ln2_b, hbuf);

    // FC1: 1024 blocks, BN=128
    k_gemm<1, 0, 1, 128><<<dim3(FFDIM / 128, NTOK / 128), 256, 0, stream>>>(
        hbuf, wt_fc1, b_fc1, nullptr, nullptr, hgelu, NTOK, FFDIM, D_MODEL);

    // FC2: BN=64 -> 512 blocks (2 blocks/CU + pipeline)
    k_gemm<0, 1, 0, 64><<<dim3(D_MODEL / 64, NTOK / 128), 256, 0, stream>>>(
        hgelu, wt_fc2, b_fc2, out, out, nullptr, NTOK, D_MODEL, FFDIM);
}